// Round 4
// baseline (277.735 us; speedup 1.0000x reference)
//
#include <hip/hip_runtime.h>
#include <hip/hip_bf16.h>
#include <math.h>

#define N 8192
#define M 8192
#define D 64

typedef __bf16 bf16x8 __attribute__((ext_vector_type(8)));
typedef float f32x4 __attribute__((ext_vector_type(4)));

// ---------------------------------------------------------------------------
// Prep: split fp32 rows into bf16 hi/lo + fp32 row norms, stored in
// MFMA-fragment order (dense 1 KB loads in the main kernel).
// ---------------------------------------------------------------------------
__global__ __launch_bounds__(256) void prep_kernel(
    const float* __restrict__ x, const float* __restrict__ y,
    __bf16* __restrict__ xsh, __bf16* __restrict__ xsl, float* __restrict__ xn,
    __bf16* __restrict__ ysh, __bf16* __restrict__ ysl, float* __restrict__ yn)
{
    int t   = threadIdx.x;
    int row = blockIdx.x * 32 + (t >> 3);
    int c   = t & 7;                       // chunk: k = c>>2, quad = c&3

    const float* src;
    __bf16 *ph, *pl;
    float* nrm;
    int r;
    bool isx = row < N;
    if (isx) { src = x; ph = xsh; pl = xsl; nrm = xn; r = row; }
    else     { src = y; ph = ysh; pl = ysl; nrm = yn; r = row - N; }

    const float* p = src + (size_t)r * D + c * 8;
    f32x4 a = *reinterpret_cast<const f32x4*>(p);
    f32x4 b = *reinterpret_cast<const f32x4*>(p + 4);
    float v[8] = {a[0], a[1], a[2], a[3], b[0], b[1], b[2], b[3]};

    bf16x8 hv, lv;
    float s = 0.0f;
    #pragma unroll
    for (int i = 0; i < 8; ++i) {
        float vi = v[i];
        __bf16 hi = (__bf16)vi;            // RNE round to bf16
        float lof = vi - (float)hi;        // exact residual
        hv[i] = hi;
        lv[i] = (__bf16)lof;
        s += vi * vi;
    }
    s += __shfl_down(s, 4);
    s += __shfl_down(s, 2);
    s += __shfl_down(s, 1);

    int g = r >> 6, m = r & 63;
    int slot;
    if (isx) slot = ((m >> 4) * 2 + (c >> 2)) * 64 + (c & 3) * 16 + (m & 15);
    else     slot = ((m & 3)  * 2 + (c >> 2)) * 64 + (c & 3) * 16 + (m >> 2);
    size_t idx = (size_t)g * 4096 + (size_t)slot * 8;

    *reinterpret_cast<bf16x8*>(ph + idx) = hv;
    *reinterpret_cast<bf16x8*>(pl + idx) = lv;
    if (c == 0) nrm[r] = s;
}

// ---------------------------------------------------------------------------
// Main: 128x128 tile per 256-thread block; 64x64 per wave.
// bf16x3 split precision via 16x16x32 MFMA (xh*yh + xh*yl + xl*yh).
// Lean epilogue: out = exp2(min(c2*acc + brt, 0)) where
//   c    = -0.5/sigma^2 * log2(e),  c2 = -2*c,  brt = c*(xn[r]+yn[t]).
// min(arg,0) == clamp(sqd,0) since c < 0.  Per element: fma + min + exp2.
// Output: nontemporal f32x4 stores (cols 4*l16..+3 contiguous; 256 B/row x 4
// rows per instruction).
// ---------------------------------------------------------------------------
__global__ __launch_bounds__(256) void rbf_kernel(
    const __bf16* __restrict__ xsh, const __bf16* __restrict__ xsl,
    const float* __restrict__ xn,
    const __bf16* __restrict__ ysh, const __bf16* __restrict__ ysl,
    const float* __restrict__ yn,
    const float* __restrict__ sig, float* __restrict__ out)
{
    int tid  = threadIdx.x;
    int wave = tid >> 6;
    int lane = tid & 63;
    int quad = lane >> 4;
    int l16  = lane & 15;

    int i_base = blockIdx.y * 128 + (wave >> 1) * 64;
    int j_base = blockIdx.x * 128 + (wave & 1) * 64;

    float s = sig[0];
    const float log2e = 1.4426950408889634f;
    float c  = -0.5f / (s * s) * log2e;    // < 0
    float c2 = -2.0f * c;

    // B fragments: dense loads, resident across the ti loop (64 VGPRs).
    const __bf16* pbh = ysh + (size_t)(j_base >> 6) * 4096 + lane * 8;
    const __bf16* pbl = ysl + (size_t)(j_base >> 6) * 4096 + lane * 8;
    bf16x8 Bh[4][2], Bl[4][2];
    #pragma unroll
    for (int t = 0; t < 4; ++t)
        #pragma unroll
        for (int k = 0; k < 2; ++k) {
            Bh[t][k] = *reinterpret_cast<const bf16x8*>(pbh + (t * 2 + k) * 512);
            Bl[t][k] = *reinterpret_cast<const bf16x8*>(pbl + (t * 2 + k) * 512);
        }
    f32x4 ynv = *reinterpret_cast<const f32x4*>(yn + j_base + 4 * l16);
    f32x4 by;                              // c * yn[t]
    #pragma unroll
    for (int t = 0; t < 4; ++t) by[t] = c * ynv[t];

    const __bf16* pah = xsh + (size_t)(i_base >> 6) * 4096 + lane * 8;
    const __bf16* pal = xsl + (size_t)(i_base >> 6) * 4096 + lane * 8;

    #pragma unroll
    for (int ti = 0; ti < 4; ++ti) {
        bf16x8 Ah[2], Al[2];
        #pragma unroll
        for (int k = 0; k < 2; ++k) {
            Ah[k] = *reinterpret_cast<const bf16x8*>(pah + (ti * 2 + k) * 512);
            Al[k] = *reinterpret_cast<const bf16x8*>(pal + (ti * 2 + k) * 512);
        }
        f32x4 xnv = *reinterpret_cast<const f32x4*>(xn + i_base + ti * 16 + quad * 4);

        f32x4 acc[4];
        #pragma unroll
        for (int t = 0; t < 4; ++t) acc[t] = (f32x4){0.f, 0.f, 0.f, 0.f};

        #pragma unroll
        for (int k = 0; k < 2; ++k)
            #pragma unroll
            for (int t = 0; t < 4; ++t) {
                acc[t] = __builtin_amdgcn_mfma_f32_16x16x32_bf16(Ah[k], Bh[t][k], acc[t], 0, 0, 0);
                acc[t] = __builtin_amdgcn_mfma_f32_16x16x32_bf16(Ah[k], Bl[t][k], acc[t], 0, 0, 0);
                acc[t] = __builtin_amdgcn_mfma_f32_16x16x32_bf16(Al[k], Bh[t][k], acc[t], 0, 0, 0);
            }

        // brt[r][t] = c*xn[r] + c*yn[t], hoisted: 4 fma + 16 add per ti.
        f32x4 brt[4];
        #pragma unroll
        for (int r = 0; r < 4; ++r) {
            float bx = __builtin_fmaf(c, xnv[r], 0.0f);
            #pragma unroll
            for (int t = 0; t < 4; ++t) brt[r][t] = bx + by[t];
        }

        #pragma unroll
        for (int r = 0; r < 4; ++r) {
            int row = i_base + ti * 16 + quad * 4 + r;
            f32x4 v;
            #pragma unroll
            for (int t = 0; t < 4; ++t) {
                float arg = __builtin_fmaf(c2, acc[t][r], brt[r][t]);
                arg = fminf(arg, 0.0f);
                v[t] = __builtin_amdgcn_exp2f(arg);
            }
            __builtin_nontemporal_store(
                v, reinterpret_cast<f32x4*>(out + (size_t)row * M + j_base + 4 * l16));
        }
    }
}

extern "C" void kernel_launch(void* const* d_in, const int* in_sizes, int n_in,
                              void* d_out, int out_size, void* d_ws, size_t ws_size,
                              hipStream_t stream) {
    const float* x   = (const float*)d_in[0];
    const float* y   = (const float*)d_in[1];
    const float* sig = (const float*)d_in[2];
    float* out = (float*)d_out;

    char* ws = (char*)d_ws;
    __bf16* xsh = (__bf16*)(ws);
    __bf16* xsl = (__bf16*)(ws + (1u << 20));
    __bf16* ysh = (__bf16*)(ws + (2u << 20));
    __bf16* ysl = (__bf16*)(ws + (3u << 20));
    float*  xn  = (float*) (ws + (4u << 20));
    float*  yn  = (float*) (ws + (4u << 20) + (1u << 15));

    prep_kernel<<<(N + M) / 32, 256, 0, stream>>>(x, y, xsh, xsl, xn, ysh, ysl, yn);

    dim3 grid(M / 128, N / 128);
    rbf_kernel<<<grid, 256, 0, stream>>>(xsh, xsl, xn, ysh, ysl, yn, sig, out);
}

// Round 5
// 268.544 us; speedup vs baseline: 1.0342x; 1.0342x over previous
//
#include <hip/hip_runtime.h>
#include <hip/hip_bf16.h>
#include <math.h>

#define N 8192
#define M 8192
#define D 64

typedef __bf16 bf16x8 __attribute__((ext_vector_type(8)));
typedef float f32x4 __attribute__((ext_vector_type(4)));

// ---------------------------------------------------------------------------
// Prep: split fp32 rows into bf16 hi/lo + fp32 row norms, stored in
// MFMA-fragment order (dense 1 KB loads in the main kernel).
// ---------------------------------------------------------------------------
__global__ __launch_bounds__(256) void prep_kernel(
    const float* __restrict__ x, const float* __restrict__ y,
    __bf16* __restrict__ xsh, __bf16* __restrict__ xsl, float* __restrict__ xn,
    __bf16* __restrict__ ysh, __bf16* __restrict__ ysl, float* __restrict__ yn)
{
    int t   = threadIdx.x;
    int row = blockIdx.x * 32 + (t >> 3);
    int c   = t & 7;                       // chunk: k = c>>2, quad = c&3

    const float* src;
    __bf16 *ph, *pl;
    float* nrm;
    int r;
    bool isx = row < N;
    if (isx) { src = x; ph = xsh; pl = xsl; nrm = xn; r = row; }
    else     { src = y; ph = ysh; pl = ysl; nrm = yn; r = row - N; }

    const float* p = src + (size_t)r * D + c * 8;
    f32x4 a = *reinterpret_cast<const f32x4*>(p);
    f32x4 b = *reinterpret_cast<const f32x4*>(p + 4);
    float v[8] = {a[0], a[1], a[2], a[3], b[0], b[1], b[2], b[3]};

    bf16x8 hv, lv;
    float s = 0.0f;
    #pragma unroll
    for (int i = 0; i < 8; ++i) {
        float vi = v[i];
        __bf16 hi = (__bf16)vi;            // RNE round to bf16
        float lof = vi - (float)hi;        // exact residual
        hv[i] = hi;
        lv[i] = (__bf16)lof;
        s += vi * vi;
    }
    s += __shfl_down(s, 4);
    s += __shfl_down(s, 2);
    s += __shfl_down(s, 1);

    int g = r >> 6, m = r & 63;
    int slot;
    if (isx) slot = ((m >> 4) * 2 + (c >> 2)) * 64 + (c & 3) * 16 + (m & 15);
    else     slot = ((m & 3)  * 2 + (c >> 2)) * 64 + (c & 3) * 16 + (m >> 2);
    size_t idx = (size_t)g * 4096 + (size_t)slot * 8;

    *reinterpret_cast<bf16x8*>(ph + idx) = hv;
    *reinterpret_cast<bf16x8*>(pl + idx) = lv;
    if (c == 0) nrm[r] = s;
}

// ---------------------------------------------------------------------------
// Main: 128x128 tile per 256-thread block; 64x64 per wave.
// bf16x3 split precision via 16x16x32 MFMA (xh*yh + xh*yl + xl*yh).
// __launch_bounds__(256, 4): cap VGPR at 128 -> 4 waves/SIMD so more store
// instructions are in flight against HBM write backpressure (the binding
// constraint; kernel is write-bound at ~4.3 TB/s vs 6.45 TB/s fill rate).
// Epilogue kept register-lean: arg = fma(c2, acc, c*(xn_r + yn_t)), clamp via
// min(arg,0) (valid since c<0), exp2.
// Output: nontemporal f32x4 stores (cols 4*l16..+3 contiguous).
// C/D: n = lane&15, m = quad*4 + reg  (verified m89/m91); B col = jb+4*l16+t.
// ---------------------------------------------------------------------------
__global__ __launch_bounds__(256, 4) void rbf_kernel(
    const __bf16* __restrict__ xsh, const __bf16* __restrict__ xsl,
    const float* __restrict__ xn,
    const __bf16* __restrict__ ysh, const __bf16* __restrict__ ysl,
    const float* __restrict__ yn,
    const float* __restrict__ sig, float* __restrict__ out)
{
    int tid  = threadIdx.x;
    int wave = tid >> 6;
    int lane = tid & 63;
    int quad = lane >> 4;
    int l16  = lane & 15;

    int i_base = blockIdx.y * 128 + (wave >> 1) * 64;
    int j_base = blockIdx.x * 128 + (wave & 1) * 64;

    float s = sig[0];
    const float log2e = 1.4426950408889634f;
    float c  = -0.5f / (s * s) * log2e;    // < 0
    float c2 = -2.0f * c;

    // B fragments: dense loads, resident across the ti loop (64 VGPRs).
    const __bf16* pbh = ysh + (size_t)(j_base >> 6) * 4096 + lane * 8;
    const __bf16* pbl = ysl + (size_t)(j_base >> 6) * 4096 + lane * 8;
    bf16x8 Bh[4][2], Bl[4][2];
    #pragma unroll
    for (int t = 0; t < 4; ++t)
        #pragma unroll
        for (int k = 0; k < 2; ++k) {
            Bh[t][k] = *reinterpret_cast<const bf16x8*>(pbh + (t * 2 + k) * 512);
            Bl[t][k] = *reinterpret_cast<const bf16x8*>(pbl + (t * 2 + k) * 512);
        }
    f32x4 ynv = *reinterpret_cast<const f32x4*>(yn + j_base + 4 * l16);

    const __bf16* pah = xsh + (size_t)(i_base >> 6) * 4096 + lane * 8;
    const __bf16* pal = xsl + (size_t)(i_base >> 6) * 4096 + lane * 8;

    #pragma unroll
    for (int ti = 0; ti < 4; ++ti) {
        bf16x8 Ah[2], Al[2];
        #pragma unroll
        for (int k = 0; k < 2; ++k) {
            Ah[k] = *reinterpret_cast<const bf16x8*>(pah + (ti * 2 + k) * 512);
            Al[k] = *reinterpret_cast<const bf16x8*>(pal + (ti * 2 + k) * 512);
        }
        f32x4 xnv = *reinterpret_cast<const f32x4*>(xn + i_base + ti * 16 + quad * 4);

        f32x4 acc[4];
        #pragma unroll
        for (int t = 0; t < 4; ++t) acc[t] = (f32x4){0.f, 0.f, 0.f, 0.f};

        #pragma unroll
        for (int k = 0; k < 2; ++k)
            #pragma unroll
            for (int t = 0; t < 4; ++t) {
                acc[t] = __builtin_amdgcn_mfma_f32_16x16x32_bf16(Ah[k], Bh[t][k], acc[t], 0, 0, 0);
                acc[t] = __builtin_amdgcn_mfma_f32_16x16x32_bf16(Ah[k], Bl[t][k], acc[t], 0, 0, 0);
                acc[t] = __builtin_amdgcn_mfma_f32_16x16x32_bf16(Al[k], Bh[t][k], acc[t], 0, 0, 0);
            }

        #pragma unroll
        for (int r = 0; r < 4; ++r) {
            int row = i_base + ti * 16 + quad * 4 + r;
            f32x4 v;
            #pragma unroll
            for (int t = 0; t < 4; ++t) {
                float arg = __builtin_fmaf(c2, acc[t][r], c * (xnv[r] + ynv[t]));
                arg = fminf(arg, 0.0f);
                v[t] = __builtin_amdgcn_exp2f(arg);
            }
            __builtin_nontemporal_store(
                v, reinterpret_cast<f32x4*>(out + (size_t)row * M + j_base + 4 * l16));
        }
    }
}

extern "C" void kernel_launch(void* const* d_in, const int* in_sizes, int n_in,
                              void* d_out, int out_size, void* d_ws, size_t ws_size,
                              hipStream_t stream) {
    const float* x   = (const float*)d_in[0];
    const float* y   = (const float*)d_in[1];
    const float* sig = (const float*)d_in[2];
    float* out = (float*)d_out;

    char* ws = (char*)d_ws;
    __bf16* xsh = (__bf16*)(ws);
    __bf16* xsl = (__bf16*)(ws + (1u << 20));
    __bf16* ysh = (__bf16*)(ws + (2u << 20));
    __bf16* ysl = (__bf16*)(ws + (3u << 20));
    float*  xn  = (float*) (ws + (4u << 20));
    float*  yn  = (float*) (ws + (4u << 20) + (1u << 15));

    prep_kernel<<<(N + M) / 32, 256, 0, stream>>>(x, y, xsh, xsl, xn, ysh, ysl, yn);

    dim3 grid(M / 128, N / 128);
    rbf_kernel<<<grid, 256, 0, stream>>>(xsh, xsl, xn, ysh, ysl, yn, sig, out);
}